// Round 2
// baseline (5078.970 us; speedup 1.0000x reference)
//
#include <hip/hip_runtime.h>

// VanillaRNN: h_{t+1} = tanh(W_hx x_t + W_hh h_t + b_h), T=1024, H=512, B=256.
// R15: homogeneous multi-column MFMA. R14 post-mortem: wave specialization
// (1 VALU + 1 MFMA wave per SIMD) broke R13's co-issue VALU saturation
// (2900 VALU-cy/step at 50% busy vs R13's 2700 @ 80%). Key insight: per-WG
// MFMA count for the 512x512 GEMV is 512 regardless of how many batch
// columns share the B operand -> pack 16 columns/WG (16 WGs, 1/CU):
//   - B operand = 16 DIFFERENT h vectors (100% of the 16 N-slots used)
//   - each wave owns 64 rows x full k=512 -> full-k accumulation in regs,
//     NO partial-reduce phase; ONE barrier/step (double-buffered hs)
//   - all 8 waves identical MFMA waves (2/SIMD co-issue, 4 indep acc chains)
//   - bias + W_hx*x_t folded into MFMA C-init; tail = tanh+pack only
// Floor: 512 MFMA x 5.15 cy/CU = 2637 cy/step; DS 128 b128 ~1200 cy
// (overlapped); tail+barrier ~350 -> ~3000 cy/step ~ 1.25 us -> ~1280 us.
// Layout facts used (HW-verified): A row = lane&15, k = 8*(lane>>4)+j
// (R14 passed with per-row data), D col = lane&15, row = 4*(lane>>4)+q (m89),
// B symmetric to A: col = lane&15, k = 8*(lane>>4)+j (m90-family refchecked).
// LDS strides: all ≡ 4 (mod 32) dwords -> even bank spread on B reads
// (8/bank = minimum for 1 KB/instr), 2-way max elsewhere.

#define T_SEQ    1024
#define HID      512
#define NTHREADS 512
#define NW       8
#define NCLS     10
#define COLS     16     // batch columns per WG
#define NTILE    4      // 16-row tiles per wave (wave owns 64 rows)
#define KSTEPS   16     // 512 / 32
#define HSTR     520    // _Float16 units; 260 dwords ≡ 4 (mod 32)
#define XSTR     1028   // float units; ≡ 4 (mod 32)
#define HFSTR    516    // float units; ≡ 4 (mod 32)

typedef _Float16 half2_t __attribute__((ext_vector_type(2)));
typedef _Float16 half8_t __attribute__((ext_vector_type(8)));
typedef float    f32x4_t __attribute__((ext_vector_type(4)));

#if __has_builtin(__builtin_amdgcn_sched_barrier)
#define SCHED_BARRIER() __builtin_amdgcn_sched_barrier(0)
#else
#define SCHED_BARRIER()
#endif

__device__ __forceinline__ unsigned int pack2(float a, float b) {
    half2_t h = {(_Float16)a, (_Float16)b};
    return __builtin_bit_cast(unsigned int, h);
}

__device__ __forceinline__ float fast_tanh(float s) {
    // tanh(s) = 1 - 2/(e^{2s}+1); exp2(s*2*log2e). Exact at +/-inf.
#if __has_builtin(__builtin_amdgcn_exp2f)
    float e = __builtin_amdgcn_exp2f(s * 2.885390081777927f);
#else
    float e = __expf(2.0f * s);
#endif
    return 1.0f - 2.0f / (e + 1.0f);
}

__global__ __attribute__((amdgpu_flat_work_group_size(NTHREADS, NTHREADS)))
           __attribute__((amdgpu_waves_per_eu(2, 2)))
void rnn_mfma(
    const float* __restrict__ x, const float* __restrict__ h_init,
    const float* __restrict__ W_hx, const float* __restrict__ W_hh,
    const float* __restrict__ b_h, const float* __restrict__ W_ph,
    const float* __restrict__ b_p, float* __restrict__ out)
{
    __shared__ __align__(16) _Float16 hs[2][COLS * HSTR];  // 33.3 KB, dbuf h
    __shared__ __align__(16) float    xs[COLS * XSTR];     // 65.8 KB, x staged
    __shared__ __align__(16) float    hfin[COLS * HFSTR];  // 33.0 KB, final h f32

    const int tid  = threadIdx.x;
    const int w    = tid >> 6;        // wave: owns rows [64w, 64w+64)
    const int lane = tid & 63;
    const int col  = lane & 15;       // MFMA M/N index (A row, B col, D col)
    const int g    = lane >> 4;       // k-group (8-wide chunk within k=32)
    const int col0 = blockIdx.x * COLS;

    // Stage x for this WG's 16 batch columns.
    for (int i = tid; i < COLS * T_SEQ; i += NTHREADS) {
        const int c = i >> 10, t = i & (T_SEQ - 1);
        xs[c * XSTR + t] = x[(size_t)(col0 + c) * T_SEQ + t];
    }
    // h_init broadcast to all 16 columns (reference broadcasts [H,1] -> [H,B]).
    for (int i = tid; i < COLS * HID; i += NTHREADS) {
        const int c = i >> 9, r = i & (HID - 1);
        hs[0][c * HSTR + r] = (_Float16)h_init[r];
    }

    // A fragments: lane (col,g) of wave w, tile tt holds
    // W_hh[64w+16tt+col][32ks+8g .. +8) for ks = 0..15. 256 words -> unified
    // VGPR/AGPR file (MFMA reads A from AGPR natively; R13 proved ~350/wave
    // at 2 waves/SIMD).
    half8_t afrag[NTILE][KSTEPS];
    float   whxr[NTILE][4], bhr[NTILE][4];
    #pragma unroll
    for (int tt = 0; tt < NTILE; ++tt) {
        const float* rowp = W_hh + (size_t)(64 * w + 16 * tt + col) * HID + 8 * g;
        #pragma unroll
        for (int ks = 0; ks < KSTEPS; ++ks) {
            float4 v0 = *(const float4*)(rowp + 32 * ks);
            float4 v1 = *(const float4*)(rowp + 32 * ks + 4);
            half8_t a = {(_Float16)v0.x, (_Float16)v0.y, (_Float16)v0.z, (_Float16)v0.w,
                         (_Float16)v1.x, (_Float16)v1.y, (_Float16)v1.z, (_Float16)v1.w};
            afrag[tt][ks] = a;
            if ((ks & 3) == 3) SCHED_BARRIER();   // cap init-phase pressure
        }
        // D readout rows for this lane (m89 map): 4g+q within tile.
        #pragma unroll
        for (int q = 0; q < 4; ++q) {
            const int rr = 64 * w + 16 * tt + 4 * g + q;
            whxr[tt][q] = W_hx[rr];
            bhr[tt][q]  = b_h[rr];
        }
        SCHED_BARRIER();
    }
    // Opaque pin: block rematerialization of packed A values.
    #pragma unroll
    for (int tt = 0; tt < NTILE; ++tt)
        #pragma unroll
        for (int ks = 0; ks < KSTEPS; ++ks)
            asm volatile("" : "+v"(afrag[tt][ks]));

    __syncthreads();

    #pragma unroll 1
    for (int t = 0; t < T_SEQ; ++t) {
        const int cur = t & 1;
        // B-frag base: lane (col,g) reads h_col[32ks+8g .. +8). Loop-invariant
        // base + 64B*ks immediate offsets -> 16 ds_read_b128/step.
        const _Float16* hb = &hs[cur][col * HSTR + 8 * g];
        const float xw = xs[col * XSTR + t];   // 2-way bank max (pad ≡4 mod 32)

        // C-init = whx[row]*x_col[t] + bh[row]  (folds input+bias into MFMA).
        f32x4_t acc[NTILE];
        #pragma unroll
        for (int tt = 0; tt < NTILE; ++tt) {
            f32x4_t a0;
            #pragma unroll
            for (int q = 0; q < 4; ++q) a0[q] = whxr[tt][q] * xw + bhr[tt][q];
            acc[tt] = a0;
        }

        // 64 MFMA/wave/step, 4 independent acc chains (x 2 waves/SIMD = 8).
        #pragma unroll
        for (int ks = 0; ks < KSTEPS; ++ks) {
            half8_t bf = *(const half8_t*)(hb + 32 * ks);
            #pragma unroll
            for (int tt = 0; tt < NTILE; ++tt)
                acc[tt] = __builtin_amdgcn_mfma_f32_16x16x32_f16(
                              afrag[tt][ks], bf, acc[tt], 0, 0, 0);
        }

        // Tail: tanh + pack + publish h (lane owns D rows 4g..4g+3 of its col).
        _Float16* hn = &hs[cur ^ 1][col * HSTR];
        #pragma unroll
        for (int tt = 0; tt < NTILE; ++tt) {
            const float v0 = fast_tanh(acc[tt][0]);
            const float v1 = fast_tanh(acc[tt][1]);
            const float v2 = fast_tanh(acc[tt][2]);
            const float v3 = fast_tanh(acc[tt][3]);
            *(uint2*)&hn[64 * w + 16 * tt + 4 * g] =
                make_uint2(pack2(v0, v1), pack2(v2, v3));
            if (t == T_SEQ - 1)   // uniform branch, taken once
                *(float4*)&hfin[col * HFSTR + 64 * w + 16 * tt + 4 * g] =
                    make_float4(v0, v1, v2, v3);
        }

        __syncthreads();   // dbuf hs => one barrier/step is sufficient
    }

    // Epilogue: p = W_ph @ h_last + b_p for this WG's 16 columns.
    // Half-wave (32 lanes) per column: wave w handles cols 2w, 2w+1.
    {
        const int sub = lane >> 5, l32 = lane & 31;
        const int cl  = 2 * w + sub;          // 0..15
        #pragma unroll 1
        for (int c = 0; c < NCLS; ++c) {
            float s = 0.0f;
            #pragma unroll
            for (int j = 0; j < 16; ++j) {
                const int r = l32 + 32 * j;
                s += W_ph[c * HID + r] * hfin[cl * HFSTR + r];
            }
            #pragma unroll
            for (int off = 16; off; off >>= 1) s += __shfl_down(s, off, 64);
            if (l32 == 0) out[(size_t)(col0 + cl) * NCLS + c] = s + b_p[c];
        }
    }
}

extern "C" void kernel_launch(void* const* d_in, const int* in_sizes, int n_in,
                              void* d_out, int out_size, void* d_ws, size_t ws_size,
                              hipStream_t stream) {
    const float* x      = (const float*)d_in[0];
    const float* h_init = (const float*)d_in[1];
    const float* W_hx   = (const float*)d_in[2];
    const float* W_hh   = (const float*)d_in[3];
    const float* b_h    = (const float*)d_in[4];
    const float* W_ph   = (const float*)d_in[5];
    const float* b_p    = (const float*)d_in[6];
    float* out = (float*)d_out;

    const int B   = in_sizes[0] / T_SEQ;   // 256 batch columns
    const int nwg = B / COLS;              // 16 WGs, one per CU
    rnn_mfma<<<nwg, NTHREADS, 0, stream>>>(x, h_init, W_hx, W_hh, b_h, W_ph, b_p, out);
}

// Round 3
// 3162.698 us; speedup vs baseline: 1.6059x; 1.6059x over previous
//
#include <hip/hip_runtime.h>

// VanillaRNN: h_{t+1} = tanh(W_hx x_t + W_hh h_t + b_h), T=1024, H=512, B=256.
// R16 = R15 (homogeneous multi-column MFMA) with the SPILL fixed.
// R15 post-mortem: afrag = 256 dwords/lane == entire AGPR budget at
// 2 waves/SIMD -> allocator spilled to scratch (WRITE_SIZE 16KB -> 2.5MB,
// per-step ~512KB/WG L2 re-reads == measured 4.9 us/step). R13 proved
// ~224 W-dwords/lane + small working set fits; so:
//   - ksteps 0..12 of A in regs (208 dwords/lane), ksteps 13..15 in LDS
//     (96 KB; lane-major uint4, conflict-free b128)
//   - x staged in 256-step chunks (16.6 KB instead of 65.8 KB)
//   - final f32 h aliases the A-LDS region after the last barrier
//   LDS total 144.8 KB <= 160 KB.
// Structure (unchanged from R15): 16 WGs x 16 batch cols, 1 WG/CU, 8 waves,
// wave w owns rows [64w,64w+64) x full k -> no partial reduce, ONE
// barrier/step (dbuf h). B operand = 16 different h vectors (all N slots
// used). C-init = whx*x+bh folded into MFMA. Layout facts HW-verified
// (R14/R15 passed): A row = lane&15 / k = 8*(lane>>4)+j; D col = lane&15,
// row = 4*(lane>>4)+q (m89); B symmetric to A.
// Budget/step/CU: MFMA 512 x 5.15cy = 2637 cy floor; LDS (B 128KB + A 96KB)
// = 2070 cy @112B/cy hidden under MFMA; tanh tail ~350 + barrier ~100
// -> ~3100 cy ~ 1.3 us/step -> ~1250-1350 us (R13: 1434).

#define T_SEQ    1024
#define HID      512
#define NTHREADS 512
#define NCLS     10
#define COLS     16     // batch columns per WG
#define NTILE    4      // 16-row tiles per wave (wave owns 64 rows)
#define KSTEPS   16     // 512 / 32
#define KREG     13     // ksteps 0..12 in regs (208 dwords/lane)
#define KLDS     3      // ksteps 13..15 in LDS
#define HSTR     520    // _Float16 units; 260 dwords == 4 (mod 32)
#define HSB      (COLS * HSTR)   // 8320 f16 per h buffer
#define CHUNK    256    // x staging chunk (steps)
#define CHMASK   (CHUNK - 1)
#define XSTR_C   260    // floats per col in x chunk; == 4 (mod 32)
#define HFSTR    516    // floats; == 4 (mod 32)

// LDS layout (bytes)
#define OFF_HS    0                        // 2*8320*2        = 33280
#define OFF_ALDS  33280                    // 8*4*3*64*16     = 98304
#define OFF_XS    (33280 + 98304)          // 16*260*4        = 16640
#define SMEM_SZ   (OFF_XS + 16640)         // 148224 <= 163840

typedef _Float16 half2_t __attribute__((ext_vector_type(2)));
typedef _Float16 half8_t __attribute__((ext_vector_type(8)));
typedef float    f32x4_t __attribute__((ext_vector_type(4)));

#if __has_builtin(__builtin_amdgcn_sched_barrier)
#define SCHED_BARRIER() __builtin_amdgcn_sched_barrier(0)
#else
#define SCHED_BARRIER()
#endif

__device__ __forceinline__ unsigned int pack2(float a, float b) {
    half2_t h = {(_Float16)a, (_Float16)b};
    return __builtin_bit_cast(unsigned int, h);
}

__device__ __forceinline__ float fast_tanh(float s) {
    // tanh(s) = 1 - 2/(e^{2s}+1); exp2(s*2*log2e). Exact at +/-inf.
#if __has_builtin(__builtin_amdgcn_exp2f)
    float e = __builtin_amdgcn_exp2f(s * 2.885390081777927f);
#else
    float e = __expf(2.0f * s);
#endif
    return 1.0f - 2.0f / (e + 1.0f);
}

__global__ __attribute__((amdgpu_flat_work_group_size(NTHREADS, NTHREADS)))
           __attribute__((amdgpu_waves_per_eu(2, 2)))
void rnn_mfma(
    const float* __restrict__ x, const float* __restrict__ h_init,
    const float* __restrict__ W_hx, const float* __restrict__ W_hh,
    const float* __restrict__ b_h, const float* __restrict__ W_ph,
    const float* __restrict__ b_p, float* __restrict__ out)
{
    __shared__ __align__(16) unsigned char smem[SMEM_SZ];
    _Float16* hs   = (_Float16*)(smem + OFF_HS);    // [2][COLS*HSTR]
    uint4*    Alds = (uint4*)(smem + OFF_ALDS);     // [8][NTILE][KLDS][64]
    float*    xs   = (float*)(smem + OFF_XS);       // [COLS][XSTR_C]

    const int tid  = threadIdx.x;
    const int w    = tid >> 6;        // wave: owns rows [64w, 64w+64)
    const int lane = tid & 63;
    const int col  = lane & 15;       // MFMA M/N index (A row, B col, D col)
    const int g    = lane >> 4;       // k-group (8-wide chunk within k=32)
    const int col0 = blockIdx.x * COLS;

    // h_init broadcast to all 16 columns (reference broadcasts [H,1] -> [H,B]).
    for (int i = tid; i < COLS * HID; i += NTHREADS) {
        const int c = i >> 9, r = i & (HID - 1);
        hs[c * HSTR + r] = (_Float16)h_init[r];
    }

    // A fragments: lane (col,g) of wave w, tile tt holds
    // W_hh[64w+16tt+col][32ks+8g .. +8). ksteps 0..12 -> regs (208 dwords,
    // fits the R13-proven budget); 13..15 -> LDS (lane-major, conflict-free).
    half8_t afrag[NTILE][KREG];
    float   whxr[NTILE][4], bhr[NTILE][4];
    #pragma unroll
    for (int tt = 0; tt < NTILE; ++tt) {
        const float* rowp = W_hh + (size_t)(64 * w + 16 * tt + col) * HID + 8 * g;
        #pragma unroll
        for (int ks = 0; ks < KREG; ++ks) {
            float4 v0 = *(const float4*)(rowp + 32 * ks);
            float4 v1 = *(const float4*)(rowp + 32 * ks + 4);
            half8_t a = {(_Float16)v0.x, (_Float16)v0.y, (_Float16)v0.z, (_Float16)v0.w,
                         (_Float16)v1.x, (_Float16)v1.y, (_Float16)v1.z, (_Float16)v1.w};
            afrag[tt][ks] = a;
            if ((ks & 3) == 3) SCHED_BARRIER();   // cap init-phase pressure
        }
        SCHED_BARRIER();
        #pragma unroll
        for (int ks = KREG; ks < KSTEPS; ++ks) {
            float4 v0 = *(const float4*)(rowp + 32 * ks);
            float4 v1 = *(const float4*)(rowp + 32 * ks + 4);
            Alds[((w * NTILE + tt) * KLDS + (ks - KREG)) * 64 + lane] =
                make_uint4(pack2(v0.x, v0.y), pack2(v0.z, v0.w),
                           pack2(v1.x, v1.y), pack2(v1.z, v1.w));
        }
        // D readout rows for this lane (m89 map): 4g+q within tile.
        #pragma unroll
        for (int q = 0; q < 4; ++q) {
            const int rr = 64 * w + 16 * tt + 4 * g + q;
            whxr[tt][q] = W_hx[rr];
            bhr[tt][q]  = b_h[rr];
        }
        SCHED_BARRIER();
    }
    // Opaque pin: block rematerialization of packed A values.
    #pragma unroll
    for (int tt = 0; tt < NTILE; ++tt)
        #pragma unroll
        for (int ks = 0; ks < KREG; ++ks)
            asm volatile("" : "+v"(afrag[tt][ks]));

    __syncthreads();   // h_init + Alds visible

    f32x4_t acc[NTILE];   // lives past the loop: last step's sums feed epilogue

    #pragma unroll 1
    for (int t = 0; t < T_SEQ; ++t) {
        if ((t & CHMASK) == 0) {   // x chunk refill (4x over the loop)
            for (int i = tid; i < COLS * CHUNK; i += NTHREADS) {
                const int c = i >> 8, j = i & CHMASK;
                xs[c * XSTR_C + j] = x[(size_t)(col0 + c) * T_SEQ + t + j];
            }
            __syncthreads();
        }
        const int cur = t & 1;
        const _Float16* hb = hs + cur * HSB + col * HSTR + 8 * g;
        const float xw = xs[col * XSTR_C + (t & CHMASK)];

        // C-init = whx[row]*x_col[t] + bh[row] (folds input+bias into MFMA).
        #pragma unroll
        for (int tt = 0; tt < NTILE; ++tt) {
            f32x4_t a0;
            #pragma unroll
            for (int q = 0; q < 4; ++q) a0[q] = whxr[tt][q] * xw + bhr[tt][q];
            acc[tt] = a0;
        }

        // 64 MFMA/wave/step, 4 independent acc chains (x2 waves/SIMD = 8).
        #pragma unroll
        for (int ks = 0; ks < KREG; ++ks) {
            half8_t bf = *(const half8_t*)(hb + 32 * ks);
            #pragma unroll
            for (int tt = 0; tt < NTILE; ++tt)
                acc[tt] = __builtin_amdgcn_mfma_f32_16x16x32_f16(
                              afrag[tt][ks], bf, acc[tt], 0, 0, 0);
        }
        #pragma unroll
        for (int ks = KREG; ks < KSTEPS; ++ks) {
            half8_t bf = *(const half8_t*)(hb + 32 * ks);
            #pragma unroll
            for (int tt = 0; tt < NTILE; ++tt) {
                half8_t a = __builtin_bit_cast(half8_t,
                    Alds[((w * NTILE + tt) * KLDS + (ks - KREG)) * 64 + lane]);
                acc[tt] = __builtin_amdgcn_mfma_f32_16x16x32_f16(
                              a, bf, acc[tt], 0, 0, 0);
            }
        }

        // Tail: tanh + pack + publish h (lane owns D rows 4g..4g+3 of its col).
        _Float16* hn = hs + (cur ^ 1) * HSB + col * HSTR + 64 * w;
        #pragma unroll
        for (int tt = 0; tt < NTILE; ++tt) {
            const float v0 = fast_tanh(acc[tt][0]);
            const float v1 = fast_tanh(acc[tt][1]);
            const float v2 = fast_tanh(acc[tt][2]);
            const float v3 = fast_tanh(acc[tt][3]);
            *(uint2*)&hn[16 * tt + 4 * g] =
                make_uint2(pack2(v0, v1), pack2(v2, v3));
        }

        __syncthreads();   // dbuf hs => one barrier/step is sufficient
    }

    // Final h in f32: recompute tanh from the still-live last-step acc and
    // stage into the (now dead) A-LDS region. The loop's final barrier
    // guarantees all Alds reads are done before aliasing.
    float* hfin = (float*)(smem + OFF_ALDS);   // [COLS][HFSTR]
    #pragma unroll
    for (int tt = 0; tt < NTILE; ++tt) {
        const float v0 = fast_tanh(acc[tt][0]);
        const float v1 = fast_tanh(acc[tt][1]);
        const float v2 = fast_tanh(acc[tt][2]);
        const float v3 = fast_tanh(acc[tt][3]);
        *(float4*)&hfin[col * HFSTR + 64 * w + 16 * tt + 4 * g] =
            make_float4(v0, v1, v2, v3);
    }
    __syncthreads();

    // Epilogue: p = W_ph @ h_last + b_p for this WG's 16 columns.
    // Half-wave (32 lanes) per column: wave w handles cols 2w, 2w+1.
    {
        const int sub = lane >> 5, l32 = lane & 31;
        const int cl  = 2 * w + sub;          // 0..15
        #pragma unroll 1
        for (int c = 0; c < NCLS; ++c) {
            float s = 0.0f;
            #pragma unroll
            for (int j = 0; j < 16; ++j) {
                const int r = l32 + 32 * j;
                s += W_ph[c * HID + r] * hfin[cl * HFSTR + r];
            }
            #pragma unroll
            for (int off = 16; off; off >>= 1) s += __shfl_down(s, off, 64);
            if (l32 == 0) out[(size_t)(col0 + cl) * NCLS + c] = s + b_p[c];
        }
    }
}

extern "C" void kernel_launch(void* const* d_in, const int* in_sizes, int n_in,
                              void* d_out, int out_size, void* d_ws, size_t ws_size,
                              hipStream_t stream) {
    const float* x      = (const float*)d_in[0];
    const float* h_init = (const float*)d_in[1];
    const float* W_hx   = (const float*)d_in[2];
    const float* W_hh   = (const float*)d_in[3];
    const float* b_h    = (const float*)d_in[4];
    const float* W_ph   = (const float*)d_in[5];
    const float* b_p    = (const float*)d_in[6];
    float* out = (float*)d_out;

    const int B   = in_sizes[0] / T_SEQ;   // 256 batch columns
    const int nwg = B / COLS;              // 16 WGs, one per CU
    rnn_mfma<<<nwg, NTHREADS, 0, stream>>>(x, h_init, W_hx, W_hh, b_h, W_ph, b_p, out);
}